// Round 2
// baseline (587621.338 us; speedup 1.0000x reference)
//
#include <hip/hip_runtime.h>
#include <hip/hip_cooperative_groups.h>
#include <cstddef>

namespace cg = cooperative_groups;

#define T_STEPS 16384
#define E_DIM   1024
#define H_DIM   1024
#define G4      4096

#define NWG 128   // cooperative workgroups (<= 256 CUs, 1 block/CU)
#define NTH 512   // threads per wg (8 waves)
#define EPW 8     // h elements owned per wg (1024/128)
#define CH  256   // timesteps per chunk (xg chunk buffer = CH*4096 fp32 = 4 MiB)
#define NCHUNK (T_STEPS / CH)
#define TKc 32    // GEMM k-tile

__device__ __forceinline__ float sigmoid_f(float x) {
    return 1.f / (1.f + __expf(-x));
}
__device__ __forceinline__ float tanh_f(float x) {
    return 1.f - 2.f / (__expf(2.f * x) + 1.f);  // exact limits at +-inf
}

// One fused cooperative kernel:
//  per chunk: [GEMM xg for 256 steps] -> grid.sync -> [256 recurrent steps, 1 sync each]
//  epilogue: in-kernel loss reduction, single scalar to out.
__global__ __launch_bounds__(NTH) void lstm_fused_kernel(
    const float* __restrict__ Xs, const float* __restrict__ Wih,
    const float* __restrict__ Whh, const float* __restrict__ bih,
    const float* __restrict__ bhh, const int* __restrict__ ys,
    float* __restrict__ xgc,       // CH*4096 floats (rotating chunk buffer)
    float* __restrict__ hbuf,      // 2*H floats (double buffer)
    float* __restrict__ partials,  // NWG*T floats: partials[w*T + t] = wg-partial exp-sum
    float* __restrict__ hy,        // T floats: h_t[y_t]
    float* __restrict__ wsum,      // NWG floats
    float* __restrict__ out)       // 1 float
{
    cg::grid_group grid = cg::this_grid();
    const int w    = blockIdx.x;
    const int tid  = threadIdx.x;
    const int lane = tid & 63;
    const int wv   = tid >> 6;       // wave 0..7
    const int base8 = w * EPW;

    __shared__ float As[TKc][68];    // 64-row A tile, transposed, +4 pad
    __shared__ float Bs[TKc][132];   // 128-row B tile, transposed, +4 pad
    __shared__ float hs[H_DIM];
    __shared__ float gacc[32];
    __shared__ float c_s[EPW];
    __shared__ float red[8];

    if (tid < EPW) c_s[tid] = 0.f;
    {   // zero both h buffers (wgs 0..3 cover 2048 floats)
        int g = w * NTH + tid;
        if (g < 2 * H_DIM) hbuf[g] = 0.f;
    }

    // ---- W_hh fragment in registers: wave wv owns gate rows fi = wv*4+u ----
    // fi -> global row R = (fi>>3)*1024 + base8 + (fi&7); lane covers k = lane + 64m
    float Wreg[4][16];
#pragma unroll
    for (int u = 0; u < 4; ++u) {
        int fi = wv * 4 + u;
        int R  = ((fi >> 3) << 10) + base8 + (fi & 7);
#pragma unroll
        for (int m = 0; m < 16; ++m)
            Wreg[u][m] = Whh[(size_t)R * H_DIM + lane + (m << 6)];
    }

    // ---- GEMM tile mapping: wg -> one 64x128 tile of a 256x4096 chunk ----
    const int mt   = w >> 5;           // 0..3  (row tile within chunk)
    const int nt   = w & 31;           // 0..31 (col tile)
    const int n0   = nt * 128;
    const int tx4  = (tid & 31) * 4;   // 0..124
    const int ty4  = (tid >> 5) * 4;   // 0..60
    const int lrow = tid >> 3;         // 0..63
    const int lkg  = (tid & 7) * 4;    // 0..28

    float4 bias_v;
    {
        const float4 bi = *(const float4*)&bih[n0 + tx4];
        const float4 bh = *(const float4*)&bhh[n0 + tx4];
        bias_v.x = bi.x + bh.x; bias_v.y = bi.y + bh.y;
        bias_v.z = bi.z + bh.z; bias_v.w = bi.w + bh.w;
    }

    float xg_i = 0.f, xg_f = 0.f, xg_g = 0.f, xg_o = 0.f;
    int ynext = (wv == 0 && lane < EPW) ? ys[0] : 0;

    for (int c = 0; c < NCHUNK; ++c) {
        const int t0 = c * CH;

        // ================= GEMM phase: xgc = Xs[t0:t0+CH] @ Wih^T + bias =================
        float acc[4][4];
#pragma unroll
        for (int i = 0; i < 4; ++i)
#pragma unroll
            for (int j = 0; j < 4; ++j) acc[i][j] = 0.f;

        const float* Arow = Xs + (size_t)(t0 + mt * 64 + lrow) * E_DIM + lkg;

        for (int kc = 0; kc < E_DIM; kc += TKc) {
            __syncthreads();
            float4 av = *(const float4*)(Arow + kc);
            As[lkg + 0][lrow] = av.x; As[lkg + 1][lrow] = av.y;
            As[lkg + 2][lrow] = av.z; As[lkg + 3][lrow] = av.w;
#pragma unroll
            for (int rep = 0; rep < 2; ++rep) {
                int br = rep * 64 + lrow;
                float4 bv = *(const float4*)&Wih[(size_t)(n0 + br) * E_DIM + kc + lkg];
                Bs[lkg + 0][br] = bv.x; Bs[lkg + 1][br] = bv.y;
                Bs[lkg + 2][br] = bv.z; Bs[lkg + 3][br] = bv.w;
            }
            __syncthreads();
#pragma unroll
            for (int kk = 0; kk < TKc; ++kk) {
                float4 a = *(const float4*)&As[kk][ty4];
                float4 b = *(const float4*)&Bs[kk][tx4];
                acc[0][0] = fmaf(a.x, b.x, acc[0][0]); acc[0][1] = fmaf(a.x, b.y, acc[0][1]);
                acc[0][2] = fmaf(a.x, b.z, acc[0][2]); acc[0][3] = fmaf(a.x, b.w, acc[0][3]);
                acc[1][0] = fmaf(a.y, b.x, acc[1][0]); acc[1][1] = fmaf(a.y, b.y, acc[1][1]);
                acc[1][2] = fmaf(a.y, b.z, acc[1][2]); acc[1][3] = fmaf(a.y, b.w, acc[1][3]);
                acc[2][0] = fmaf(a.z, b.x, acc[2][0]); acc[2][1] = fmaf(a.z, b.y, acc[2][1]);
                acc[2][2] = fmaf(a.z, b.z, acc[2][2]); acc[2][3] = fmaf(a.z, b.w, acc[2][3]);
                acc[3][0] = fmaf(a.w, b.x, acc[3][0]); acc[3][1] = fmaf(a.w, b.y, acc[3][1]);
                acc[3][2] = fmaf(a.w, b.z, acc[3][2]); acc[3][3] = fmaf(a.w, b.w, acc[3][3]);
            }
        }
#pragma unroll
        for (int i = 0; i < 4; ++i) {
            int lr = mt * 64 + ty4 + i;   // chunk-local row
            float4 ov;
            ov.x = acc[i][0] + bias_v.x; ov.y = acc[i][1] + bias_v.y;
            ov.z = acc[i][2] + bias_v.z; ov.w = acc[i][3] + bias_v.w;
            *(float4*)&xgc[(size_t)lr * G4 + n0 + tx4] = ov;
        }
        __threadfence();
        grid.sync();   // xgc chunk visible to all wgs (cross-XCD)

        // prefetch xg for first step of chunk
        if (wv == 0 && lane < EPW) {
            const float* xr = xgc + base8 + lane;
            xg_i = xr[0]; xg_f = xr[H_DIM]; xg_g = xr[2 * H_DIM]; xg_o = xr[3 * H_DIM];
        }

        // ================= recurrence phase: CH serial steps =================
        for (int lt = 0; lt < CH; ++lt) {
            const int t = t0 + lt;
            const float* hr = hbuf + (t & 1) * H_DIM;
            hs[tid]       = hr[tid];
            hs[tid + NTH] = hr[tid + NTH];
            __syncthreads();

            float hv[16];
#pragma unroll
            for (int m = 0; m < 16; ++m) hv[m] = hs[lane + (m << 6)];

            float a0 = 0.f, a1 = 0.f, a2 = 0.f, a3 = 0.f;
#pragma unroll
            for (int m = 0; m < 16; ++m) {
                a0 = fmaf(Wreg[0][m], hv[m], a0);
                a1 = fmaf(Wreg[1][m], hv[m], a1);
                a2 = fmaf(Wreg[2][m], hv[m], a2);
                a3 = fmaf(Wreg[3][m], hv[m], a3);
            }
#pragma unroll
            for (int off = 32; off >= 1; off >>= 1) {
                a0 += __shfl_xor(a0, off);
                a1 += __shfl_xor(a1, off);
                a2 += __shfl_xor(a2, off);
                a3 += __shfl_xor(a3, off);
            }
            if (lane < 4) {
                float v = (lane == 0) ? a0 : (lane == 1) ? a1 : (lane == 2) ? a2 : a3;
                gacc[wv * 4 + lane] = v;   // index fi = g*8 + r
            }
            __syncthreads();

            if (wv == 0 && lane < EPW) {
                int j  = lane;
                int gj = base8 + j;
                float gi = gacc[0 * EPW + j] + xg_i;
                float gf = gacc[1 * EPW + j] + xg_f;
                float gg = gacc[2 * EPW + j] + xg_g;
                float go = gacc[3 * EPW + j] + xg_o;
                float ii = sigmoid_f(gi);
                float ff = sigmoid_f(gf);
                float g2 = tanh_f(gg);
                float oo = sigmoid_f(go);
                float cc = fmaf(ff, c_s[j], ii * g2);
                c_s[j] = cc;
                float h = oo * tanh_f(cc);
                hbuf[((t + 1) & 1) * H_DIM + gj] = h;
                float e = __expf(h);           // h in (-1,1): no max subtraction needed
                if (gj == ynext) hy[t] = h;
                // sum e over the 8 owning lanes
                e += __shfl_xor(e, 4);
                e += __shfl_xor(e, 2);
                e += __shfl_xor(e, 1);
                if (lane == 0) partials[(size_t)w * T_STEPS + t] = e;
                // prefetch next step's xg (within chunk only) + next label
                if (lt + 1 < CH) {
                    const float* xr = xgc + (size_t)(lt + 1) * G4 + base8 + lane;
                    xg_i = xr[0]; xg_f = xr[H_DIM];
                    xg_g = xr[2 * H_DIM]; xg_o = xr[3 * H_DIM];
                }
                if (t + 1 < T_STEPS) ynext = ys[t + 1];
            }
            __syncthreads();      // protect gacc/hs WAR even if grid.sync lacks a block barrier
            __threadfence();      // release hbuf/partials/hy across XCDs
            grid.sync();
        }
    }

    // ================= epilogue: loss = sum_t [log(S_t) - h_t[y_t]] =================
    float val = 0.f;
    {
        int t = w * NTH + tid;   // wgs 0..31 cover all T
        if (t < T_STEPS) {
            float s = 0.f;
            for (int i = 0; i < NWG; ++i) s += partials[(size_t)i * T_STEPS + t];
            val = logf(s) - hy[t];
        }
    }
#pragma unroll
    for (int off = 32; off >= 1; off >>= 1) val += __shfl_xor(val, off);
    if (lane == 0) red[wv] = val;
    __syncthreads();
    if (tid == 0) {
        float s = 0.f;
#pragma unroll
        for (int i = 0; i < 8; ++i) s += red[i];
        wsum[w] = s;
    }
    __threadfence();
    grid.sync();
    if (w == 0 && tid == 0) {
        float s = 0.f;
        for (int i = 0; i < NWG; ++i) s += wsum[i];
        out[0] = s;
    }
}

// ---------------- launch ----------------
extern "C" void kernel_launch(void* const* d_in, const int* in_sizes, int n_in,
                              void* d_out, int out_size, void* d_ws, size_t ws_size,
                              hipStream_t stream)
{
    const float* Xs  = (const float*)d_in[0];
    const float* Wih = (const float*)d_in[1];
    const float* Whh = (const float*)d_in[2];
    const float* bih = (const float*)d_in[3];
    const float* bhh = (const float*)d_in[4];
    const int*   ys  = (const int*)d_in[5];

    // workspace layout: 12.7 MiB total
    float* ws       = (float*)d_ws;
    float* xgc      = ws;                                    // CH*4096      = 1,048,576 f
    float* hbuf     = xgc + (size_t)CH * G4;                 // 2048 f
    float* partials = hbuf + 2 * H_DIM;                      // NWG*T        = 2,097,152 f
    float* hy       = partials + (size_t)NWG * T_STEPS;      // T            = 16,384 f
    float* wsum     = hy + T_STEPS;                          // NWG          = 128 f
    float* out      = (float*)d_out;

    void* args[] = {(void*)&Xs, (void*)&Wih, (void*)&Whh, (void*)&bih, (void*)&bhh,
                    (void*)&ys, (void*)&xgc, (void*)&hbuf, (void*)&partials,
                    (void*)&hy, (void*)&wsum, (void*)&out};
    hipLaunchCooperativeKernel((void*)lstm_fused_kernel,
                               dim3(NWG), dim3(NTH), args, 0, stream);
}

// Round 3
// 40794.904 us; speedup vs baseline: 14.4043x; 14.4043x over previous
//
#include <hip/hip_runtime.h>
#include <hip/hip_cooperative_groups.h>
#include <cstddef>

namespace cg = cooperative_groups;

#define T_STEPS 16384
#define E_DIM   1024
#define H_DIM   1024
#define G4      4096

#define NWG 128   // cooperative workgroups (1 per CU, 128 of 256 CUs)
#define NTH 512   // threads per wg (8 waves)
#define EPW 8     // h elements owned per wg (1024/128)
#define CH  256   // timesteps per chunk (xg chunk buffer = CH*4096 fp32 = 4 MiB)
#define NCHUNK (T_STEPS / CH)
#define TKc 32    // GEMM k-tile
#define NSLOT 4   // h exchange rotation depth (skew bound is ~1 step; 4 is safe)

__device__ __forceinline__ float sigmoid_f(float x) {
    return 1.f / (1.f + __expf(-x));
}
__device__ __forceinline__ float tanh_f(float x) {
    return 1.f - 2.f / (__expf(2.f * x) + 1.f);  // exact limits at +-inf
}

// h exchange: hslot[s*1024 + j] = (tag << 32) | float_bits, tag = t for h_t, s = t%NSLOT.
// Published/consumed with relaxed AGENT-scope atomics (per-access coherent across XCDs,
// no fences, no barrier). Self-validating: consumers spin until tag matches.

__global__ __launch_bounds__(NTH) void lstm_fused_kernel(
    const float* __restrict__ Xs, const float* __restrict__ Wih,
    const float* __restrict__ Whh, const float* __restrict__ bih,
    const float* __restrict__ bhh, const int* __restrict__ ys,
    float* __restrict__ xgc,                    // CH*4096 floats (rotating chunk buffer)
    unsigned long long* __restrict__ hslot,     // NSLOT*1024 packed h entries
    float* __restrict__ partials,               // NWG*T: partials[w*T + t]
    float* __restrict__ hy,                     // T floats: h_t[y_t]
    float* __restrict__ wsum,                   // NWG floats
    float* __restrict__ out)                    // 1 float
{
    cg::grid_group grid = cg::this_grid();
    const int w    = blockIdx.x;
    const int tid  = threadIdx.x;
    const int lane = tid & 63;
    const int wv   = tid >> 6;       // wave 0..7
    const int base8 = w * EPW;

    __shared__ float As[TKc][68];    // 64-row A tile, transposed, +4 pad
    __shared__ float Bs[TKc][132];   // 128-row B tile, transposed, +4 pad
    __shared__ float hs[H_DIM];
    __shared__ float gacc[32];
    __shared__ float c_s[EPW];
    __shared__ float red[8];

    if (tid < EPW) c_s[tid] = 0.f;

    // publish h_0 = 0 (tag 0, bits 0 -> whole u64 is 0) for this wg's 8 slots
    if (wv == 0 && lane < EPW) {
        __hip_atomic_store(&hslot[base8 + lane], 0ull,
                           __ATOMIC_RELAXED, __HIP_MEMORY_SCOPE_AGENT);
    }

    // ---- W_hh fragment in registers: wave wv owns gate rows fi = wv*4+u ----
    // fi -> global row R = (fi>>3)*1024 + base8 + (fi&7); lane covers k = lane + 64m
    float Wreg[4][16];
#pragma unroll
    for (int u = 0; u < 4; ++u) {
        int fi = wv * 4 + u;
        int R  = ((fi >> 3) << 10) + base8 + (fi & 7);
#pragma unroll
        for (int m = 0; m < 16; ++m)
            Wreg[u][m] = Whh[(size_t)R * H_DIM + lane + (m << 6)];
    }

    // ---- GEMM tile mapping: wg -> one 64x128 tile of a 256x4096 chunk ----
    const int mt   = w >> 5;           // 0..3  (row tile within chunk)
    const int nt   = w & 31;           // 0..31 (col tile)
    const int n0   = nt * 128;
    const int tx4  = (tid & 31) * 4;   // 0..124
    const int ty4  = (tid >> 5) * 4;   // 0..60
    const int lrow = tid >> 3;         // 0..63
    const int lkg  = (tid & 7) * 4;    // 0..28

    float4 bias_v;
    {
        const float4 bi = *(const float4*)&bih[n0 + tx4];
        const float4 bh = *(const float4*)&bhh[n0 + tx4];
        bias_v.x = bi.x + bh.x; bias_v.y = bi.y + bh.y;
        bias_v.z = bi.z + bh.z; bias_v.w = bi.w + bh.w;
    }

    float xg_i = 0.f, xg_f = 0.f, xg_g = 0.f, xg_o = 0.f;
    int ynext = (wv == 0 && lane < EPW) ? ys[0] : 0;

    for (int c = 0; c < NCHUNK; ++c) {
        const int t0 = c * CH;

        // ================= GEMM phase: xgc = Xs[t0:t0+CH] @ Wih^T + bias =================
        float acc[4][4];
#pragma unroll
        for (int i = 0; i < 4; ++i)
#pragma unroll
            for (int j = 0; j < 4; ++j) acc[i][j] = 0.f;

        const float* Arow = Xs + (size_t)(t0 + mt * 64 + lrow) * E_DIM + lkg;

        for (int kc = 0; kc < E_DIM; kc += TKc) {
            __syncthreads();
            float4 av = *(const float4*)(Arow + kc);
            As[lkg + 0][lrow] = av.x; As[lkg + 1][lrow] = av.y;
            As[lkg + 2][lrow] = av.z; As[lkg + 3][lrow] = av.w;
#pragma unroll
            for (int rep = 0; rep < 2; ++rep) {
                int br = rep * 64 + lrow;
                float4 bv = *(const float4*)&Wih[(size_t)(n0 + br) * E_DIM + kc + lkg];
                Bs[lkg + 0][br] = bv.x; Bs[lkg + 1][br] = bv.y;
                Bs[lkg + 2][br] = bv.z; Bs[lkg + 3][br] = bv.w;
            }
            __syncthreads();
#pragma unroll
            for (int kk = 0; kk < TKc; ++kk) {
                float4 a = *(const float4*)&As[kk][ty4];
                float4 b = *(const float4*)&Bs[kk][tx4];
                acc[0][0] = fmaf(a.x, b.x, acc[0][0]); acc[0][1] = fmaf(a.x, b.y, acc[0][1]);
                acc[0][2] = fmaf(a.x, b.z, acc[0][2]); acc[0][3] = fmaf(a.x, b.w, acc[0][3]);
                acc[1][0] = fmaf(a.y, b.x, acc[1][0]); acc[1][1] = fmaf(a.y, b.y, acc[1][1]);
                acc[1][2] = fmaf(a.y, b.z, acc[1][2]); acc[1][3] = fmaf(a.y, b.w, acc[1][3]);
                acc[2][0] = fmaf(a.z, b.x, acc[2][0]); acc[2][1] = fmaf(a.z, b.y, acc[2][1]);
                acc[2][2] = fmaf(a.z, b.z, acc[2][2]); acc[2][3] = fmaf(a.z, b.w, acc[2][3]);
                acc[3][0] = fmaf(a.w, b.x, acc[3][0]); acc[3][1] = fmaf(a.w, b.y, acc[3][1]);
                acc[3][2] = fmaf(a.w, b.z, acc[3][2]); acc[3][3] = fmaf(a.w, b.w, acc[3][3]);
            }
        }
#pragma unroll
        for (int i = 0; i < 4; ++i) {
            int lr = mt * 64 + ty4 + i;   // chunk-local row
            float4 ov;
            ov.x = acc[i][0] + bias_v.x; ov.y = acc[i][1] + bias_v.y;
            ov.z = acc[i][2] + bias_v.z; ov.w = acc[i][3] + bias_v.w;
            *(float4*)&xgc[(size_t)lr * G4 + n0 + tx4] = ov;
        }
        __threadfence();
        grid.sync();   // xgc chunk visible to all wgs (once per 256 steps)

        // prefetch xg for first step of chunk
        if (wv == 0 && lane < EPW) {
            const float* xr = xgc + base8 + lane;
            xg_i = xr[0]; xg_f = xr[H_DIM]; xg_g = xr[2 * H_DIM]; xg_o = xr[3 * H_DIM];
        }

        // ================= recurrence phase: CH serial steps, NO grid barrier =================
        for (int lt = 0; lt < CH; ++lt) {
            const int t = t0 + lt;

            // ---- stage h_t into LDS: poll own 2 packed slots until tag == t ----
            {
                const unsigned tag = (unsigned)t;
                unsigned long long* p =
                    hslot + (((size_t)(t & (NSLOT - 1))) << 10) + 2 * tid;
                unsigned long long v0, v1;
                for (;;) {
                    v0 = __hip_atomic_load(p,     __ATOMIC_RELAXED, __HIP_MEMORY_SCOPE_AGENT);
                    v1 = __hip_atomic_load(p + 1, __ATOMIC_RELAXED, __HIP_MEMORY_SCOPE_AGENT);
                    if ((unsigned)(v0 >> 32) == tag && (unsigned)(v1 >> 32) == tag) break;
                }
                hs[2 * tid]     = __uint_as_float((unsigned)v0);
                hs[2 * tid + 1] = __uint_as_float((unsigned)v1);
            }
            __syncthreads();

            float hv[16];
#pragma unroll
            for (int m = 0; m < 16; ++m) hv[m] = hs[lane + (m << 6)];

            float a0 = 0.f, a1 = 0.f, a2 = 0.f, a3 = 0.f;
#pragma unroll
            for (int m = 0; m < 16; ++m) {
                a0 = fmaf(Wreg[0][m], hv[m], a0);
                a1 = fmaf(Wreg[1][m], hv[m], a1);
                a2 = fmaf(Wreg[2][m], hv[m], a2);
                a3 = fmaf(Wreg[3][m], hv[m], a3);
            }
#pragma unroll
            for (int off = 32; off >= 1; off >>= 1) {
                a0 += __shfl_xor(a0, off);
                a1 += __shfl_xor(a1, off);
                a2 += __shfl_xor(a2, off);
                a3 += __shfl_xor(a3, off);
            }
            if (lane < 4) {
                float v = (lane == 0) ? a0 : (lane == 1) ? a1 : (lane == 2) ? a2 : a3;
                gacc[wv * 4 + lane] = v;   // index fi = g*8 + r
            }
            __syncthreads();

            if (wv == 0 && lane < EPW) {
                int j  = lane;
                int gj = base8 + j;
                float gi = gacc[0 * EPW + j] + xg_i;
                float gf = gacc[1 * EPW + j] + xg_f;
                float gg = gacc[2 * EPW + j] + xg_g;
                float go = gacc[3 * EPW + j] + xg_o;
                float ii = sigmoid_f(gi);
                float ff = sigmoid_f(gf);
                float g2 = tanh_f(gg);
                float oo = sigmoid_f(go);
                float cc = fmaf(ff, c_s[j], ii * g2);
                c_s[j] = cc;
                float h = oo * tanh_f(cc);
                // publish h_{t+1}: packed (tag<<32 | bits), relaxed agent store
                unsigned long long pk =
                    ((unsigned long long)(unsigned)(t + 1) << 32) |
                    (unsigned long long)__float_as_uint(h);
                __hip_atomic_store(
                    &hslot[(((size_t)((t + 1) & (NSLOT - 1))) << 10) + gj], pk,
                    __ATOMIC_RELAXED, __HIP_MEMORY_SCOPE_AGENT);
                float e = __expf(h);           // h in (-1,1): no max subtraction needed
                if (gj == ynext) hy[t] = h;
                e += __shfl_xor(e, 4);
                e += __shfl_xor(e, 2);
                e += __shfl_xor(e, 1);
                if (lane == 0) partials[(size_t)w * T_STEPS + t] = e;
                // prefetch next step's xg (within chunk only) + next label
                if (lt + 1 < CH) {
                    const float* xr = xgc + (size_t)(lt + 1) * G4 + base8 + lane;
                    xg_i = xr[0]; xg_f = xr[H_DIM];
                    xg_g = xr[2 * H_DIM]; xg_o = xr[3 * H_DIM];
                }
                if (t + 1 < T_STEPS) ynext = ys[t + 1];
            }
            __syncthreads();      // hs/gacc WAR protection before next step's staging
        }
    }

    // ================= epilogue: loss = sum_t [log(S_t) - h_t[y_t]] =================
    __threadfence();
    grid.sync();   // partials/hy visible everywhere

    float val = 0.f;
    {
        int t = w * NTH + tid;   // wgs 0..31 cover all T
        if (t < T_STEPS) {
            float s = 0.f;
            for (int i = 0; i < NWG; ++i) s += partials[(size_t)i * T_STEPS + t];
            val = logf(s) - hy[t];
        }
    }
#pragma unroll
    for (int off = 32; off >= 1; off >>= 1) val += __shfl_xor(val, off);
    if (lane == 0) red[wv] = val;
    __syncthreads();
    if (tid == 0) {
        float s = 0.f;
#pragma unroll
        for (int i = 0; i < 8; ++i) s += red[i];
        wsum[w] = s;
    }
    __threadfence();
    grid.sync();
    if (w == 0 && tid == 0) {
        float s = 0.f;
        for (int i = 0; i < NWG; ++i) s += wsum[i];
        out[0] = s;
    }
}

// ---------------- launch ----------------
extern "C" void kernel_launch(void* const* d_in, const int* in_sizes, int n_in,
                              void* d_out, int out_size, void* d_ws, size_t ws_size,
                              hipStream_t stream)
{
    const float* Xs  = (const float*)d_in[0];
    const float* Wih = (const float*)d_in[1];
    const float* Whh = (const float*)d_in[2];
    const float* bih = (const float*)d_in[3];
    const float* bhh = (const float*)d_in[4];
    const int*   ys  = (const int*)d_in[5];

    // workspace layout: ~12.2 MiB total
    float* ws = (float*)d_ws;
    float* xgc                    = ws;                               // CH*4096 = 1,048,576 f
    unsigned long long* hslot     = (unsigned long long*)(xgc + (size_t)CH * G4);  // NSLOT*1024 u64
    float* partials               = (float*)(hslot + NSLOT * H_DIM);  // NWG*T = 2,097,152 f
    float* hy                     = partials + (size_t)NWG * T_STEPS; // T f
    float* wsum                   = hy + T_STEPS;                     // NWG f
    float* out                    = (float*)d_out;

    void* args[] = {(void*)&Xs, (void*)&Wih, (void*)&Whh, (void*)&bih, (void*)&bhh,
                    (void*)&ys, (void*)&xgc, (void*)&hslot, (void*)&partials,
                    (void*)&hy, (void*)&wsum, (void*)&out};
    hipLaunchCooperativeKernel((void*)lstm_fused_kernel,
                               dim3(NWG), dim3(NTH), args, 0, stream);
}